// Round 24
// baseline (83.862 us; speedup 1.0000x reference)
//
#include <hip/hip_runtime.h>
#include <math.h>

#define EPSV 1e-6f
#define MAX_NORM (1.0f - 1e-3f)

typedef __attribute__((ext_vector_type(8))) short short8;   // 8 bf16 = 4 VGPRs
typedef __attribute__((ext_vector_type(4))) float f32x4;    // MFMA acc

// f32 -> bf16 (round-to-nearest-even), returns raw 16-bit pattern
__device__ inline ushort f32_to_bf16(float f) {
    union { float f; uint32_t u; } cv;
    cv.f = f;
    uint32_t u = cv.u;
    u += 0x7FFFu + ((u >> 16) & 1u);
    return (ushort)(u >> 16);
}

// async global -> LDS, 16 bytes per lane (dest = uniform base + lane*16)
__device__ inline void glds16(const ushort* gsrc, ushort* ldsdst) {
    auto* g = (const __attribute__((address_space(1))) uint32_t*)gsrc;
    auto* l = (__attribute__((address_space(3))) uint32_t*)ldsdst;
    __builtin_amdgcn_global_load_lds(g, l, 16, 0, 0);
}

// inline-asm ds_read_b128 (opaque to compiler waitcnt bookkeeping)
__device__ inline short8 ds_read128(const ushort* p) {
    auto* l3 = (const __attribute__((address_space(3))) ushort*)p;
    const uint32_t addr = (uint32_t)(uintptr_t)l3;
    short8 v;
    asm volatile("ds_read_b128 %0, %1" : "=&v"(v) : "v"(addr));
    return v;
}

// inline-asm global_load_dwordx4 into registers (we manage the vmcnt wait).
// NOTE: value materializes only at vmcnt-retire; safe ONLY with <=2 live
// async sets (R23 lesson: 3 sets -> allocator moves in-flight regs -> garbage).
__device__ inline short8 gload16(const ushort* p) {
    short8 v;
    asm volatile("global_load_dwordx4 %0, %1, off" : "=&v"(v) : "v"(p));
    return v;
}

// Packed (fragment-order) element offset for row r, chunk j (j = lane):
// unit (rb = r>>4, t = j>>2) at (rb*16 + t)*512; within unit, lane
// l = (j&3)*16 + (r&15), at l*8.
__device__ inline size_t pack_off(int r, int j) {
    return ((size_t)(r >> 4) * 16 + (j >> 2)) * 512
         + (size_t)(((j & 3) * 16 + (r & 15)) * 8);
}

// ---------------------------------------------------------------------------
// Kernel 1: expmap0 + clip for embeddings. One wave per row, D=512.
// ---------------------------------------------------------------------------
__global__ void rows_emb_kernel(const float* __restrict__ emb,
                                const float* __restrict__ logc,
                                float* __restrict__ xh,
                                ushort* __restrict__ xpk,
                                float* __restrict__ x2raw,
                                float* __restrict__ dxv) {
    const int D = 512;
    const int row = blockIdx.x;
    const int lane = threadIdx.x;   // 0..63

    const float4* r4 = (const float4*)(emb + (size_t)row * D);
    float4 a = r4[2 * lane];
    float4 b = r4[2 * lane + 1];

    float ss = a.x * a.x + a.y * a.y + a.z * a.z + a.w * a.w
             + b.x * b.x + b.y * b.y + b.z * b.z + b.w * b.w;
#pragma unroll
    for (int off = 32; off > 0; off >>= 1) ss += __shfl_xor(ss, off, 64);

    const float c  = expf(logc[0]);
    const float sc = sqrtf(c);

    const float tn    = sqrtf(ss);
    const float vn    = fmaxf(tn, EPSV);
    const float coeff = tanhf(sc * vn) / (sc * vn);
    const float pre   = coeff * tn;
    const float fac   = fminf(MAX_NORM / fmaxf(pre, EPSV), 1.0f);
    const float scale = coeff * fac;

    float4 oa, ob;
    oa.x = a.x * scale; oa.y = a.y * scale; oa.z = a.z * scale; oa.w = a.w * scale;
    ob.x = b.x * scale; ob.y = b.y * scale; ob.z = b.z * scale; ob.w = b.w * scale;

    float4* o4 = (float4*)(xh + (size_t)row * D);
    o4[2 * lane]     = oa;
    o4[2 * lane + 1] = ob;

    union { ushort u[8]; uint4 v; } pk;
    pk.u[0] = f32_to_bf16(oa.x); pk.u[1] = f32_to_bf16(oa.y);
    pk.u[2] = f32_to_bf16(oa.z); pk.u[3] = f32_to_bf16(oa.w);
    pk.u[4] = f32_to_bf16(ob.x); pk.u[5] = f32_to_bf16(ob.y);
    pk.u[6] = f32_to_bf16(ob.z); pk.u[7] = f32_to_bf16(ob.w);
    *(uint4*)(xpk + pack_off(row, lane)) = pk.v;

    if (lane == 0) {
        const float sq = scale * scale * ss;
        x2raw[row] = sq;
        dxv[row]   = 1.0f - c * fminf(sq, MAX_NORM * MAX_NORM);
    }
}

// ---------------------------------------------------------------------------
// Kernel 2: clip-only for centroids. One wave per row, D=512. Packed output.
// ---------------------------------------------------------------------------
__global__ void rows_cen_kernel(const float* __restrict__ cen,
                                const float* __restrict__ logc,
                                float* __restrict__ ch,
                                ushort* __restrict__ cpk,
                                float* __restrict__ y2raw,
                                float* __restrict__ dyv) {
    const int D = 512;
    const int row = blockIdx.x;
    const int lane = threadIdx.x;

    const float4* r4 = (const float4*)(cen + (size_t)row * D);
    float4 a = r4[2 * lane];
    float4 b = r4[2 * lane + 1];

    float ss = a.x * a.x + a.y * a.y + a.z * a.z + a.w * a.w
             + b.x * b.x + b.y * b.y + b.z * b.z + b.w * b.w;
#pragma unroll
    for (int off = 32; off > 0; off >>= 1) ss += __shfl_xor(ss, off, 64);

    const float c = expf(logc[0]);

    const float tn    = sqrtf(ss);
    const float scale = fminf(MAX_NORM / fmaxf(tn, EPSV), 1.0f);

    float4 oa, ob;
    oa.x = a.x * scale; oa.y = a.y * scale; oa.z = a.z * scale; oa.w = a.w * scale;
    ob.x = b.x * scale; ob.y = b.y * scale; ob.z = b.z * scale; ob.w = b.w * scale;

    float4* o4 = (float4*)(ch + (size_t)row * D);
    o4[2 * lane]     = oa;
    o4[2 * lane + 1] = ob;

    union { ushort u[8]; uint4 v; } pk;
    pk.u[0] = f32_to_bf16(oa.x); pk.u[1] = f32_to_bf16(oa.y);
    pk.u[2] = f32_to_bf16(oa.z); pk.u[3] = f32_to_bf16(oa.w);
    pk.u[4] = f32_to_bf16(ob.x); pk.u[5] = f32_to_bf16(ob.y);
    pk.u[6] = f32_to_bf16(ob.z); pk.u[7] = f32_to_bf16(ob.w);
    *(uint4*)(cpk + pack_off(row, lane)) = pk.v;

    if (lane == 0) {
        const float sq = scale * scale * ss;
        y2raw[row] = sq;
        dyv[row]   = 1.0f - c * fminf(sq, MAX_NORM * MAX_NORM);
    }
}

// ---------------------------------------------------------------------------
// Kernel 3: bf16 MFMA GEMM + Poincare epilogue.  A-DEPTH-2 (ring-of-4 glds),
// B depth-1 in registers (R21-proven, 2 async sets only).
// 128x128 tile, BKT=32, NT=16, 4 waves (2m x 2n), 3 blocks/CU.
// Body t: seam {vmcnt(2) steady / vmcnt(0) last; s_barrier} -- drains A(t)
// and B(t), leaves A(t+1) in flight (counted seam, never 0 mid-loop);
// then issue B(t+1)->regs, A(t+2)->buf (t+2)&3; 4 A ds_reads; 2 phases x
// {counted lgkmcnt; 8 MFMA}. Outstanding trace/wave at seam:
// [A(t):2][B(t):4][A(t+1):2] -> wait 2.
// Epilogue: per-wave LDS transpose + float4-coalesced stores.
// ---------------------------------------------------------------------------
#define EPST 68
#define KDIM 512
#define NT 16
#define NCOLS 4096

__global__ __launch_bounds__(256, 3)
void gemm_epi_kernel(const ushort* __restrict__ Apk,   // packed M x K bf16
                     const ushort* __restrict__ Bpk,   // packed N x K bf16
                     const float* __restrict__ x2raw,
                     const float* __restrict__ dxv,
                     const float* __restrict__ y2raw,
                     const float* __restrict__ dyv,
                     const float* __restrict__ logc,
                     float* __restrict__ out) {        // M x N
    // 32 KB: A ring-of-4 (4 x 4096 us); epilogue reuses [0,17408).
    __shared__ __align__(16) char smem[32768];
    ushort* Asm = (ushort*)smem;

    const int tid  = threadIdx.x;
    const int lane = tid & 63;
    const int wid  = tid >> 6;     // 0..3
    const int im   = wid >> 1;     // 0..1  (64-row half)
    const int in   = wid & 1;      // 0..1  (64-col half)

    const int bn = blockIdx.x;     // 0..31
    const int bm = blockIdx.y;     // 0..63

    f32x4 acc[4][4];
#pragma unroll
    for (int m = 0; m < 4; m++)
#pragma unroll
        for (int n = 0; n < 4; n++) acc[m][n] = (f32x4){0.f, 0.f, 0.f, 0.f};

    // A staging (packed): wave w stages rowblocks bm*8 + 2w, +1 (1KB each).
    const ushort* gA0 = Apk + ((size_t)(bm * 8 + 2 * wid)) * 8192 + lane * 8;
    const ushort* gA1 = gA0 + 8192;
    ushort* lA = Asm + wid * 1024;            // + buf*4096

    // B loads (packed): wave's 4 rowblocks bn*8 + in*4 + n.
    const ushort* gB = Bpk + ((size_t)(bn * 8 + in * 4)) * 8192 + lane * 8;

    // A compute-read base: units im*4 + m at im*2048 + m*512 (+ buf*4096).
    const ushort* rdA = Asm + im * 2048 + lane * 8;

    short8 bX[4], bY[4];   // B double-buffer (2 async sets, R21-proven)

    // Prologue: B(0)->bX [4], A(0)->buf0 [2], A(1)->buf1 [2].
    // Outstanding order: [B0:4][A0:2][A1:2].
#pragma unroll
    for (int n = 0; n < 4; n++) bX[n] = gload16(gB + n * 8192);
    glds16(gA0, lA);
    glds16(gA1, lA + 512);
    glds16(gA0 + 512, lA + 4096);
    glds16(gA1 + 512, lA + 4096 + 512);

    // Body at literal slot J (buf = J, B set = J&1), tile t = tb + J.
#define BODY(J, BUSE, BNXT)                                                   \
    do {                                                                      \
        const int t = tb + (J);                                               \
        if (t < NT - 1) asm volatile("s_waitcnt vmcnt(2)" ::: "memory");      \
        else            asm volatile("s_waitcnt vmcnt(0)" ::: "memory");      \
        __builtin_amdgcn_sched_barrier(0);                                    \
        __builtin_amdgcn_s_barrier();                                         \
        if (t + 1 < NT) {                                                     \
            const int ko1 = (t + 1) * 512;                                    \
            BNXT[0] = gload16(gB + 0 * 8192 + ko1);                           \
            BNXT[1] = gload16(gB + 1 * 8192 + ko1);                           \
            BNXT[2] = gload16(gB + 2 * 8192 + ko1);                           \
            BNXT[3] = gload16(gB + 3 * 8192 + ko1);                           \
        }                                                                     \
        if (t + 2 < NT) {                                                     \
            const int ko2 = (t + 2) * 512;                                    \
            glds16(gA0 + ko2, lA + (((J) + 2) & 3) * 4096);                   \
            glds16(gA1 + ko2, lA + (((J) + 2) & 3) * 4096 + 512);             \
        }                                                                     \
        const ushort* rA = rdA + (J) * 4096;                                  \
        short8 a0 = ds_read128(rA);                                           \
        short8 a1 = ds_read128(rA + 512);                                     \
        short8 a2 = ds_read128(rA + 1024);                                    \
        short8 a3 = ds_read128(rA + 1536);                                    \
        asm volatile("s_waitcnt lgkmcnt(2)" ::: "memory");                    \
        __builtin_amdgcn_sched_barrier(0);                                    \
        __builtin_amdgcn_s_setprio(1);                                        \
        _Pragma("unroll")                                                     \
        for (int n = 0; n < 4; n++) {                                         \
            acc[0][n] = __builtin_amdgcn_mfma_f32_16x16x32_bf16(              \
                a0, BUSE[n], acc[0][n], 0, 0, 0);                             \
            acc[1][n] = __builtin_amdgcn_mfma_f32_16x16x32_bf16(              \
                a1, BUSE[n], acc[1][n], 0, 0, 0);                             \
        }                                                                     \
        __builtin_amdgcn_sched_barrier(0);                                    \
        __builtin_amdgcn_s_setprio(0);                                        \
        asm volatile("s_waitcnt lgkmcnt(0)" ::: "memory");                    \
        __builtin_amdgcn_sched_barrier(0);                                    \
        __builtin_amdgcn_s_setprio(1);                                        \
        _Pragma("unroll")                                                     \
        for (int n = 0; n < 4; n++) {                                         \
            acc[2][n] = __builtin_amdgcn_mfma_f32_16x16x32_bf16(              \
                a2, BUSE[n], acc[2][n], 0, 0, 0);                             \
            acc[3][n] = __builtin_amdgcn_mfma_f32_16x16x32_bf16(              \
                a3, BUSE[n], acc[3][n], 0, 0, 0);                             \
        }                                                                     \
        __builtin_amdgcn_sched_barrier(0);                                    \
        __builtin_amdgcn_s_setprio(0);                                        \
    } while (0)

#pragma unroll 1
    for (int i = 0; i < 4; ++i) {
        const int tb = 4 * i;
        BODY(0, bX, bY);      // t=4i:   use X, load B(t+1)->Y, A(t+2)->buf2
        BODY(1, bY, bX);      // t=4i+1: use Y, ->X, buf3
        BODY(2, bX, bY);      // t=4i+2: use X, ->Y, buf0
        BODY(3, bY, bX);      // t=4i+3: use Y, ->X, buf1
    }
#undef BODY

    __syncthreads();   // staging LDS -> epilogue reuse safety

    // ---------------- Epilogue: LDS transpose + coalesced stores ------------
    const float c   = expf(logc[0]);
    const float rsc = 1.0f / sqrtf(c);
    const int l16 = lane & 15;
    const int lg  = lane >> 4;

    float* ep = (float*)(smem + (size_t)wid * 4352);   // [16][EPST]
    const int gr_base = bm * 128 + im * 64;
    const int gc_base = bn * 128 + in * 64;

#pragma unroll
    for (int m = 0; m < 4; m++) {
        // scatter this m-frag (16 rows x 64 cols) into the private region
#pragma unroll
        for (int n = 0; n < 4; n++)
#pragma unroll
            for (int r = 0; r < 4; r++)
                ep[(lg * 4 + r) * EPST + n * 16 + l16] = acc[m][n][r];
        asm volatile("s_waitcnt lgkmcnt(0)" ::: "memory");

        // read back row-major: 4 iters x (4 rows x 16 float4 chunks)
#pragma unroll
        for (int it = 0; it < 4; it++) {
            const int row = it * 4 + lg;                  // 0..15
            const int gr  = gr_base + m * 16 + row;
            const int gc  = gc_base + l16 * 4;
            float4 xy4 = *(const float4*)&ep[row * EPST + l16 * 4];
            const float rx  = x2raw[gr];
            const float dxr = dxv[gr];
            const float4 ry4 = *(const float4*)&y2raw[gc];
            const float4 dy4 = *(const float4*)&dyv[gc];
            float4 o;
            {
                const float rden = __builtin_amdgcn_rcpf(fmaxf(dxr * dy4.x, EPSV));
                float t = fmaxf(2.0f * c * (rx + ry4.x - 2.0f * xy4.x) * rden, EPSV);
                o.x = __logf(1.0f + t + __builtin_amdgcn_sqrtf(t * (t + 2.0f))) * rsc;
            }
            {
                const float rden = __builtin_amdgcn_rcpf(fmaxf(dxr * dy4.y, EPSV));
                float t = fmaxf(2.0f * c * (rx + ry4.y - 2.0f * xy4.y) * rden, EPSV);
                o.y = __logf(1.0f + t + __builtin_amdgcn_sqrtf(t * (t + 2.0f))) * rsc;
            }
            {
                const float rden = __builtin_amdgcn_rcpf(fmaxf(dxr * dy4.z, EPSV));
                float t = fmaxf(2.0f * c * (rx + ry4.z - 2.0f * xy4.z) * rden, EPSV);
                o.z = __logf(1.0f + t + __builtin_amdgcn_sqrtf(t * (t + 2.0f))) * rsc;
            }
            {
                const float rden = __builtin_amdgcn_rcpf(fmaxf(dxr * dy4.w, EPSV));
                float t = fmaxf(2.0f * c * (rx + ry4.w - 2.0f * xy4.w) * rden, EPSV);
                o.w = __logf(1.0f + t + __builtin_amdgcn_sqrtf(t * (t + 2.0f))) * rsc;
            }
            *(float4*)&out[(size_t)gr * NCOLS + gc] = o;
        }
        asm volatile("s_waitcnt lgkmcnt(0)" ::: "memory");
    }
}

// ---------------------------------------------------------------------------
extern "C" void kernel_launch(void* const* d_in, const int* in_sizes, int n_in,
                              void* d_out, int out_size, void* d_ws, size_t ws_size,
                              hipStream_t stream) {
    const float* emb  = (const float*)d_in[0];   // (B, D) f32
    const float* logc = (const float*)d_in[1];   // scalar f32
    const float* cen  = (const float*)d_in[2];   // (C, D) f32

    const int D = 512;
    const int B = in_sizes[0] / D;   // 8192
    const int C = in_sizes[2] / D;   // 4096

    float* out   = (float*)d_out;
    float* dists = out;                          // B*C
    float* xh    = out + (size_t)B * C;          // B*D
    float* ch    = xh + (size_t)B * D;           // C*D

    char* ws = (char*)d_ws;
    size_t off = 0;
    auto alloc = [&](size_t bytes) -> char* {
        char* p = ws + off;
        off += (bytes + 255) & ~(size_t)255;
        return p;
    };
    ushort* xpk   = (ushort*)alloc((size_t)B * D * sizeof(ushort));
    ushort* cpk   = (ushort*)alloc((size_t)C * D * sizeof(ushort));
    float*  x2raw = (float*)alloc((size_t)B * sizeof(float));
    float*  dxv   = (float*)alloc((size_t)B * sizeof(float));
    float*  y2raw = (float*)alloc((size_t)C * sizeof(float));
    float*  dyv   = (float*)alloc((size_t)C * sizeof(float));

    rows_emb_kernel<<<B, 64, 0, stream>>>(emb, logc, xh, xpk, x2raw, dxv);
    rows_cen_kernel<<<C, 64, 0, stream>>>(cen, logc, ch, cpk, y2raw, dyv);

    dim3 grid(C / 128, B / 128);   // (32, 64) = 2048 blocks
    gemm_epi_kernel<<<grid, 256, 0, stream>>>(xpk, cpk, x2raw, dxv, y2raw, dyv,
                                              logc, dists);
}

// Round 25
// 83.737 us; speedup vs baseline: 1.0015x; 1.0015x over previous
//
#include <hip/hip_runtime.h>
#include <math.h>

#define EPSV 1e-6f
#define MAX_NORM (1.0f - 1e-3f)

typedef __attribute__((ext_vector_type(8))) short short8;   // 8 bf16 = 4 VGPRs
typedef __attribute__((ext_vector_type(4))) float f32x4;    // MFMA acc

// f32 -> bf16 (round-to-nearest-even), returns raw 16-bit pattern
__device__ inline ushort f32_to_bf16(float f) {
    union { float f; uint32_t u; } cv;
    cv.f = f;
    uint32_t u = cv.u;
    u += 0x7FFFu + ((u >> 16) & 1u);
    return (ushort)(u >> 16);
}

// async global -> LDS, 16 bytes per lane (dest = uniform base + lane*16)
__device__ inline void glds16(const ushort* gsrc, ushort* ldsdst) {
    auto* g = (const __attribute__((address_space(1))) uint32_t*)gsrc;
    auto* l = (__attribute__((address_space(3))) uint32_t*)ldsdst;
    __builtin_amdgcn_global_load_lds(g, l, 16, 0, 0);
}

// inline-asm ds_read_b128 (opaque to compiler waitcnt bookkeeping)
__device__ inline short8 ds_read128(const ushort* p) {
    auto* l3 = (const __attribute__((address_space(3))) ushort*)p;
    const uint32_t addr = (uint32_t)(uintptr_t)l3;
    short8 v;
    asm volatile("ds_read_b128 %0, %1" : "=&v"(v) : "v"(addr));
    return v;
}

// inline-asm global_load_dwordx4 into registers (we manage the vmcnt wait).
// NOTE: value materializes only at vmcnt-retire; safe ONLY with <=2 live
// async sets (R23 lesson: 3 sets -> allocator moves in-flight regs -> garbage).
__device__ inline short8 gload16(const ushort* p) {
    short8 v;
    asm volatile("global_load_dwordx4 %0, %1, off" : "=&v"(v) : "v"(p));
    return v;
}

// Packed (fragment-order) element offset for row r, chunk j (j = lane):
// unit (rb = r>>4, t = j>>2) at (rb*16 + t)*512; within unit, lane
// l = (j&3)*16 + (r&15), at l*8.
__device__ inline size_t pack_off(int r, int j) {
    return ((size_t)(r >> 4) * 16 + (j >> 2)) * 512
         + (size_t)(((j & 3) * 16 + (r & 15)) * 8);
}

// ---------------------------------------------------------------------------
// Kernel 1: expmap0 + clip for embeddings. One wave per row, D=512.
// ---------------------------------------------------------------------------
__global__ void rows_emb_kernel(const float* __restrict__ emb,
                                const float* __restrict__ logc,
                                float* __restrict__ xh,
                                ushort* __restrict__ xpk,
                                float* __restrict__ x2raw,
                                float* __restrict__ dxv) {
    const int D = 512;
    const int row = blockIdx.x;
    const int lane = threadIdx.x;   // 0..63

    const float4* r4 = (const float4*)(emb + (size_t)row * D);
    float4 a = r4[2 * lane];
    float4 b = r4[2 * lane + 1];

    float ss = a.x * a.x + a.y * a.y + a.z * a.z + a.w * a.w
             + b.x * b.x + b.y * b.y + b.z * b.z + b.w * b.w;
#pragma unroll
    for (int off = 32; off > 0; off >>= 1) ss += __shfl_xor(ss, off, 64);

    const float c  = expf(logc[0]);
    const float sc = sqrtf(c);

    const float tn    = sqrtf(ss);
    const float vn    = fmaxf(tn, EPSV);
    const float coeff = tanhf(sc * vn) / (sc * vn);
    const float pre   = coeff * tn;
    const float fac   = fminf(MAX_NORM / fmaxf(pre, EPSV), 1.0f);
    const float scale = coeff * fac;

    float4 oa, ob;
    oa.x = a.x * scale; oa.y = a.y * scale; oa.z = a.z * scale; oa.w = a.w * scale;
    ob.x = b.x * scale; ob.y = b.y * scale; ob.z = b.z * scale; ob.w = b.w * scale;

    float4* o4 = (float4*)(xh + (size_t)row * D);
    o4[2 * lane]     = oa;
    o4[2 * lane + 1] = ob;

    union { ushort u[8]; uint4 v; } pk;
    pk.u[0] = f32_to_bf16(oa.x); pk.u[1] = f32_to_bf16(oa.y);
    pk.u[2] = f32_to_bf16(oa.z); pk.u[3] = f32_to_bf16(oa.w);
    pk.u[4] = f32_to_bf16(ob.x); pk.u[5] = f32_to_bf16(ob.y);
    pk.u[6] = f32_to_bf16(ob.z); pk.u[7] = f32_to_bf16(ob.w);
    *(uint4*)(xpk + pack_off(row, lane)) = pk.v;

    if (lane == 0) {
        const float sq = scale * scale * ss;
        x2raw[row] = sq;
        dxv[row]   = 1.0f - c * fminf(sq, MAX_NORM * MAX_NORM);
    }
}

// ---------------------------------------------------------------------------
// Kernel 2: clip-only for centroids. One wave per row, D=512. Packed output.
// ---------------------------------------------------------------------------
__global__ void rows_cen_kernel(const float* __restrict__ cen,
                                const float* __restrict__ logc,
                                float* __restrict__ ch,
                                ushort* __restrict__ cpk,
                                float* __restrict__ y2raw,
                                float* __restrict__ dyv) {
    const int D = 512;
    const int row = blockIdx.x;
    const int lane = threadIdx.x;

    const float4* r4 = (const float4*)(cen + (size_t)row * D);
    float4 a = r4[2 * lane];
    float4 b = r4[2 * lane + 1];

    float ss = a.x * a.x + a.y * a.y + a.z * a.z + a.w * a.w
             + b.x * b.x + b.y * b.y + b.z * b.z + b.w * b.w;
#pragma unroll
    for (int off = 32; off > 0; off >>= 1) ss += __shfl_xor(ss, off, 64);

    const float c = expf(logc[0]);

    const float tn    = sqrtf(ss);
    const float scale = fminf(MAX_NORM / fmaxf(tn, EPSV), 1.0f);

    float4 oa, ob;
    oa.x = a.x * scale; oa.y = a.y * scale; oa.z = a.z * scale; oa.w = a.w * scale;
    ob.x = b.x * scale; ob.y = b.y * scale; ob.z = b.z * scale; ob.w = b.w * scale;

    float4* o4 = (float4*)(ch + (size_t)row * D);
    o4[2 * lane]     = oa;
    o4[2 * lane + 1] = ob;

    union { ushort u[8]; uint4 v; } pk;
    pk.u[0] = f32_to_bf16(oa.x); pk.u[1] = f32_to_bf16(oa.y);
    pk.u[2] = f32_to_bf16(oa.z); pk.u[3] = f32_to_bf16(oa.w);
    pk.u[4] = f32_to_bf16(ob.x); pk.u[5] = f32_to_bf16(ob.y);
    pk.u[6] = f32_to_bf16(ob.z); pk.u[7] = f32_to_bf16(ob.w);
    *(uint4*)(cpk + pack_off(row, lane)) = pk.v;

    if (lane == 0) {
        const float sq = scale * scale * ss;
        y2raw[row] = sq;
        dyv[row]   = 1.0f - c * fminf(sq, MAX_NORM * MAX_NORM);
    }
}

// ---------------------------------------------------------------------------
// Kernel 3: bf16 MFMA GEMM + Poincare epilogue.  A-DEPTH-2 (ring-of-4 glds),
// B depth-1 in registers (R21-proven, 2 async sets only).
// 128x128 tile, BKT=32, NT=16, 4 waves (2m x 2n), 3 blocks/CU.
// Body t: seam {vmcnt(2) steady / vmcnt(0) last; s_barrier} -- drains A(t)
// and B(t), leaves A(t+1) in flight (counted seam, never 0 mid-loop);
// then issue B(t+1)->regs, A(t+2)->buf (t+2)&3; 4 A ds_reads; 2 phases x
// {counted lgkmcnt; 8 MFMA}. Outstanding trace/wave at seam:
// [A(t):2][B(t):4][A(t+1):2] -> wait 2.
// Epilogue: per-wave LDS transpose + float4-coalesced stores.
// ---------------------------------------------------------------------------
#define EPST 68
#define KDIM 512
#define NT 16
#define NCOLS 4096

__global__ __launch_bounds__(256, 3)
void gemm_epi_kernel(const ushort* __restrict__ Apk,   // packed M x K bf16
                     const ushort* __restrict__ Bpk,   // packed N x K bf16
                     const float* __restrict__ x2raw,
                     const float* __restrict__ dxv,
                     const float* __restrict__ y2raw,
                     const float* __restrict__ dyv,
                     const float* __restrict__ logc,
                     float* __restrict__ out) {        // M x N
    // 32 KB: A ring-of-4 (4 x 4096 us); epilogue reuses [0,17408).
    __shared__ __align__(16) char smem[32768];
    ushort* Asm = (ushort*)smem;

    const int tid  = threadIdx.x;
    const int lane = tid & 63;
    const int wid  = tid >> 6;     // 0..3
    const int im   = wid >> 1;     // 0..1  (64-row half)
    const int in   = wid & 1;      // 0..1  (64-col half)

    const int bn = blockIdx.x;     // 0..31
    const int bm = blockIdx.y;     // 0..63

    f32x4 acc[4][4];
#pragma unroll
    for (int m = 0; m < 4; m++)
#pragma unroll
        for (int n = 0; n < 4; n++) acc[m][n] = (f32x4){0.f, 0.f, 0.f, 0.f};

    // A staging (packed): wave w stages rowblocks bm*8 + 2w, +1 (1KB each).
    const ushort* gA0 = Apk + ((size_t)(bm * 8 + 2 * wid)) * 8192 + lane * 8;
    const ushort* gA1 = gA0 + 8192;
    ushort* lA = Asm + wid * 1024;            // + buf*4096

    // B loads (packed): wave's 4 rowblocks bn*8 + in*4 + n.
    const ushort* gB = Bpk + ((size_t)(bn * 8 + in * 4)) * 8192 + lane * 8;

    // A compute-read base: units im*4 + m at im*2048 + m*512 (+ buf*4096).
    const ushort* rdA = Asm + im * 2048 + lane * 8;

    short8 bX[4], bY[4];   // B double-buffer (2 async sets, R21-proven)

    // Prologue: B(0)->bX [4], A(0)->buf0 [2], A(1)->buf1 [2].
    // Outstanding order: [B0:4][A0:2][A1:2].
#pragma unroll
    for (int n = 0; n < 4; n++) bX[n] = gload16(gB + n * 8192);
    glds16(gA0, lA);
    glds16(gA1, lA + 512);
    glds16(gA0 + 512, lA + 4096);
    glds16(gA1 + 512, lA + 4096 + 512);

    // Body at literal slot J (buf = J, B set = J&1), tile t = tb + J.
#define BODY(J, BUSE, BNXT)                                                   \
    do {                                                                      \
        const int t = tb + (J);                                               \
        if (t < NT - 1) asm volatile("s_waitcnt vmcnt(2)" ::: "memory");      \
        else            asm volatile("s_waitcnt vmcnt(0)" ::: "memory");      \
        __builtin_amdgcn_sched_barrier(0);                                    \
        __builtin_amdgcn_s_barrier();                                         \
        if (t + 1 < NT) {                                                     \
            const int ko1 = (t + 1) * 512;                                    \
            BNXT[0] = gload16(gB + 0 * 8192 + ko1);                           \
            BNXT[1] = gload16(gB + 1 * 8192 + ko1);                           \
            BNXT[2] = gload16(gB + 2 * 8192 + ko1);                           \
            BNXT[3] = gload16(gB + 3 * 8192 + ko1);                           \
        }                                                                     \
        if (t + 2 < NT) {                                                     \
            const int ko2 = (t + 2) * 512;                                    \
            glds16(gA0 + ko2, lA + (((J) + 2) & 3) * 4096);                   \
            glds16(gA1 + ko2, lA + (((J) + 2) & 3) * 4096 + 512);             \
        }                                                                     \
        const ushort* rA = rdA + (J) * 4096;                                  \
        short8 a0 = ds_read128(rA);                                           \
        short8 a1 = ds_read128(rA + 512);                                     \
        short8 a2 = ds_read128(rA + 1024);                                    \
        short8 a3 = ds_read128(rA + 1536);                                    \
        asm volatile("s_waitcnt lgkmcnt(2)" ::: "memory");                    \
        __builtin_amdgcn_sched_barrier(0);                                    \
        __builtin_amdgcn_s_setprio(1);                                        \
        _Pragma("unroll")                                                     \
        for (int n = 0; n < 4; n++) {                                         \
            acc[0][n] = __builtin_amdgcn_mfma_f32_16x16x32_bf16(              \
                a0, BUSE[n], acc[0][n], 0, 0, 0);                             \
            acc[1][n] = __builtin_amdgcn_mfma_f32_16x16x32_bf16(              \
                a1, BUSE[n], acc[1][n], 0, 0, 0);                             \
        }                                                                     \
        __builtin_amdgcn_sched_barrier(0);                                    \
        __builtin_amdgcn_s_setprio(0);                                        \
        asm volatile("s_waitcnt lgkmcnt(0)" ::: "memory");                    \
        __builtin_amdgcn_sched_barrier(0);                                    \
        __builtin_amdgcn_s_setprio(1);                                        \
        _Pragma("unroll")                                                     \
        for (int n = 0; n < 4; n++) {                                         \
            acc[2][n] = __builtin_amdgcn_mfma_f32_16x16x32_bf16(              \
                a2, BUSE[n], acc[2][n], 0, 0, 0);                             \
            acc[3][n] = __builtin_amdgcn_mfma_f32_16x16x32_bf16(              \
                a3, BUSE[n], acc[3][n], 0, 0, 0);                             \
        }                                                                     \
        __builtin_amdgcn_sched_barrier(0);                                    \
        __builtin_amdgcn_s_setprio(0);                                        \
    } while (0)

#pragma unroll 1
    for (int i = 0; i < 4; ++i) {
        const int tb = 4 * i;
        BODY(0, bX, bY);      // t=4i:   use X, load B(t+1)->Y, A(t+2)->buf2
        BODY(1, bY, bX);      // t=4i+1: use Y, ->X, buf3
        BODY(2, bX, bY);      // t=4i+2: use X, ->Y, buf0
        BODY(3, bY, bX);      // t=4i+3: use Y, ->X, buf1
    }
#undef BODY

    __syncthreads();   // staging LDS -> epilogue reuse safety

    // ---------------- Epilogue: LDS transpose + coalesced stores ------------
    const float c   = expf(logc[0]);
    const float rsc = 1.0f / sqrtf(c);
    const int l16 = lane & 15;
    const int lg  = lane >> 4;

    float* ep = (float*)(smem + (size_t)wid * 4352);   // [16][EPST]
    const int gr_base = bm * 128 + im * 64;
    const int gc_base = bn * 128 + in * 64;

#pragma unroll
    for (int m = 0; m < 4; m++) {
        // scatter this m-frag (16 rows x 64 cols) into the private region
#pragma unroll
        for (int n = 0; n < 4; n++)
#pragma unroll
            for (int r = 0; r < 4; r++)
                ep[(lg * 4 + r) * EPST + n * 16 + l16] = acc[m][n][r];
        asm volatile("s_waitcnt lgkmcnt(0)" ::: "memory");

        // read back row-major: 4 iters x (4 rows x 16 float4 chunks)
#pragma unroll
        for (int it = 0; it < 4; it++) {
            const int row = it * 4 + lg;                  // 0..15
            const int gr  = gr_base + m * 16 + row;
            const int gc  = gc_base + l16 * 4;
            float4 xy4 = *(const float4*)&ep[row * EPST + l16 * 4];
            const float rx  = x2raw[gr];
            const float dxr = dxv[gr];
            const float4 ry4 = *(const float4*)&y2raw[gc];
            const float4 dy4 = *(const float4*)&dyv[gc];
            float4 o;
            {
                const float rden = __builtin_amdgcn_rcpf(fmaxf(dxr * dy4.x, EPSV));
                float t = fmaxf(2.0f * c * (rx + ry4.x - 2.0f * xy4.x) * rden, EPSV);
                o.x = __logf(1.0f + t + __builtin_amdgcn_sqrtf(t * (t + 2.0f))) * rsc;
            }
            {
                const float rden = __builtin_amdgcn_rcpf(fmaxf(dxr * dy4.y, EPSV));
                float t = fmaxf(2.0f * c * (rx + ry4.y - 2.0f * xy4.y) * rden, EPSV);
                o.y = __logf(1.0f + t + __builtin_amdgcn_sqrtf(t * (t + 2.0f))) * rsc;
            }
            {
                const float rden = __builtin_amdgcn_rcpf(fmaxf(dxr * dy4.z, EPSV));
                float t = fmaxf(2.0f * c * (rx + ry4.z - 2.0f * xy4.z) * rden, EPSV);
                o.z = __logf(1.0f + t + __builtin_amdgcn_sqrtf(t * (t + 2.0f))) * rsc;
            }
            {
                const float rden = __builtin_amdgcn_rcpf(fmaxf(dxr * dy4.w, EPSV));
                float t = fmaxf(2.0f * c * (rx + ry4.w - 2.0f * xy4.w) * rden, EPSV);
                o.w = __logf(1.0f + t + __builtin_amdgcn_sqrtf(t * (t + 2.0f))) * rsc;
            }
            *(float4*)&out[(size_t)gr * NCOLS + gc] = o;
        }
        asm volatile("s_waitcnt lgkmcnt(0)" ::: "memory");
    }
}

// ---------------------------------------------------------------------------
extern "C" void kernel_launch(void* const* d_in, const int* in_sizes, int n_in,
                              void* d_out, int out_size, void* d_ws, size_t ws_size,
                              hipStream_t stream) {
    const float* emb  = (const float*)d_in[0];   // (B, D) f32
    const float* logc = (const float*)d_in[1];   // scalar f32
    const float* cen  = (const float*)d_in[2];   // (C, D) f32

    const int D = 512;
    const int B = in_sizes[0] / D;   // 8192
    const int C = in_sizes[2] / D;   // 4096

    float* out   = (float*)d_out;
    float* dists = out;                          // B*C
    float* xh    = out + (size_t)B * C;          // B*D
    float* ch    = xh + (size_t)B * D;           // C*D

    char* ws = (char*)d_ws;
    size_t off = 0;
    auto alloc = [&](size_t bytes) -> char* {
        char* p = ws + off;
        off += (bytes + 255) & ~(size_t)255;
        return p;
    };
    ushort* xpk   = (ushort*)alloc((size_t)B * D * sizeof(ushort));
    ushort* cpk   = (ushort*)alloc((size_t)C * D * sizeof(ushort));
    float*  x2raw = (float*)alloc((size_t)B * sizeof(float));
    float*  dxv   = (float*)alloc((size_t)B * sizeof(float));
    float*  y2raw = (float*)alloc((size_t)C * sizeof(float));
    float*  dyv   = (float*)alloc((size_t)C * sizeof(float));

    rows_emb_kernel<<<B, 64, 0, stream>>>(emb, logc, xh, xpk, x2raw, dxv);
    rows_cen_kernel<<<C, 64, 0, stream>>>(cen, logc, ch, cpk, y2raw, dyv);

    dim3 grid(C / 128, B / 128);   // (32, 64) = 2048 blocks
    gemm_epi_kernel<<<grid, 256, 0, stream>>>(xpk, cpk, x2raw, dxv, y2raw, dyv,
                                              logc, dists);
}

// Round 26
// 81.599 us; speedup vs baseline: 1.0277x; 1.0262x over previous
//
#include <hip/hip_runtime.h>
#include <math.h>

#define EPSV 1e-6f
#define MAX_NORM (1.0f - 1e-3f)

typedef __attribute__((ext_vector_type(8))) short short8;   // 8 bf16 = 4 VGPRs
typedef __attribute__((ext_vector_type(4))) float f32x4;    // MFMA acc

// f32 -> bf16 (round-to-nearest-even), returns raw 16-bit pattern
__device__ inline ushort f32_to_bf16(float f) {
    union { float f; uint32_t u; } cv;
    cv.f = f;
    uint32_t u = cv.u;
    u += 0x7FFFu + ((u >> 16) & 1u);
    return (ushort)(u >> 16);
}

// async global -> LDS, 16 bytes per lane (dest = uniform base + lane*16)
__device__ inline void glds16(const ushort* gsrc, ushort* ldsdst) {
    auto* g = (const __attribute__((address_space(1))) uint32_t*)gsrc;
    auto* l = (__attribute__((address_space(3))) uint32_t*)ldsdst;
    __builtin_amdgcn_global_load_lds(g, l, 16, 0, 0);
}

// inline-asm ds_read_b128 (opaque to compiler waitcnt bookkeeping)
__device__ inline short8 ds_read128(const ushort* p) {
    auto* l3 = (const __attribute__((address_space(3))) ushort*)p;
    const uint32_t addr = (uint32_t)(uintptr_t)l3;
    short8 v;
    asm volatile("ds_read_b128 %0, %1" : "=&v"(v) : "v"(addr));
    return v;
}

// inline-asm global_load_dwordx4 into registers (we manage the vmcnt wait).
// NOTE: value materializes only at vmcnt-retire; safe ONLY with <=2 live
// async sets (R23 lesson: 3 sets -> allocator moves in-flight regs).
__device__ inline short8 gload16(const ushort* p) {
    short8 v;
    asm volatile("global_load_dwordx4 %0, %1, off" : "=&v"(v) : "v"(p));
    return v;
}

// Packed (fragment-order) element offset for row r, chunk j (j = lane&63):
// unit (rb = r>>4, t = j>>2) at (rb*16 + t)*512; within unit, lane
// l = (j&3)*16 + (r&15), at l*8.
__device__ inline size_t pack_off(int r, int j) {
    return ((size_t)(r >> 4) * 16 + (j >> 2)) * 512
         + (size_t)(((j & 3) * 16 + (r & 15)) * 8);
}

// ---------------------------------------------------------------------------
// Kernel 1: expmap0 + clip for embeddings. 256 threads = 4 waves, each wave
// owns one row (row = blockIdx.x*4 + wid). D=512.
// ---------------------------------------------------------------------------
__global__ __launch_bounds__(256)
void rows_emb_kernel(const float* __restrict__ emb,
                     const float* __restrict__ logc,
                     float* __restrict__ xh,
                     ushort* __restrict__ xpk,
                     float* __restrict__ x2raw,
                     float* __restrict__ dxv) {
    const int D = 512;
    const int lane = threadIdx.x & 63;
    const int row  = blockIdx.x * 4 + (threadIdx.x >> 6);

    const float4* r4 = (const float4*)(emb + (size_t)row * D);
    float4 a = r4[2 * lane];
    float4 b = r4[2 * lane + 1];

    float ss = a.x * a.x + a.y * a.y + a.z * a.z + a.w * a.w
             + b.x * b.x + b.y * b.y + b.z * b.z + b.w * b.w;
#pragma unroll
    for (int off = 32; off > 0; off >>= 1) ss += __shfl_xor(ss, off, 64);

    const float c  = expf(logc[0]);
    const float sc = sqrtf(c);

    const float tn    = sqrtf(ss);
    const float vn    = fmaxf(tn, EPSV);
    const float coeff = tanhf(sc * vn) / (sc * vn);
    const float pre   = coeff * tn;
    const float fac   = fminf(MAX_NORM / fmaxf(pre, EPSV), 1.0f);
    const float scale = coeff * fac;

    float4 oa, ob;
    oa.x = a.x * scale; oa.y = a.y * scale; oa.z = a.z * scale; oa.w = a.w * scale;
    ob.x = b.x * scale; ob.y = b.y * scale; ob.z = b.z * scale; ob.w = b.w * scale;

    float4* o4 = (float4*)(xh + (size_t)row * D);
    o4[2 * lane]     = oa;
    o4[2 * lane + 1] = ob;

    union { ushort u[8]; uint4 v; } pk;
    pk.u[0] = f32_to_bf16(oa.x); pk.u[1] = f32_to_bf16(oa.y);
    pk.u[2] = f32_to_bf16(oa.z); pk.u[3] = f32_to_bf16(oa.w);
    pk.u[4] = f32_to_bf16(ob.x); pk.u[5] = f32_to_bf16(ob.y);
    pk.u[6] = f32_to_bf16(ob.z); pk.u[7] = f32_to_bf16(ob.w);
    *(uint4*)(xpk + pack_off(row, lane)) = pk.v;

    if (lane == 0) {
        const float sq = scale * scale * ss;
        x2raw[row] = sq;
        dxv[row]   = 1.0f - c * fminf(sq, MAX_NORM * MAX_NORM);
    }
}

// ---------------------------------------------------------------------------
// Kernel 2: clip-only for centroids. 4 rows per 256-thread block.
// ---------------------------------------------------------------------------
__global__ __launch_bounds__(256)
void rows_cen_kernel(const float* __restrict__ cen,
                     const float* __restrict__ logc,
                     float* __restrict__ ch,
                     ushort* __restrict__ cpk,
                     float* __restrict__ y2raw,
                     float* __restrict__ dyv) {
    const int D = 512;
    const int lane = threadIdx.x & 63;
    const int row  = blockIdx.x * 4 + (threadIdx.x >> 6);

    const float4* r4 = (const float4*)(cen + (size_t)row * D);
    float4 a = r4[2 * lane];
    float4 b = r4[2 * lane + 1];

    float ss = a.x * a.x + a.y * a.y + a.z * a.z + a.w * a.w
             + b.x * b.x + b.y * b.y + b.z * b.z + b.w * b.w;
#pragma unroll
    for (int off = 32; off > 0; off >>= 1) ss += __shfl_xor(ss, off, 64);

    const float c = expf(logc[0]);

    const float tn    = sqrtf(ss);
    const float scale = fminf(MAX_NORM / fmaxf(tn, EPSV), 1.0f);

    float4 oa, ob;
    oa.x = a.x * scale; oa.y = a.y * scale; oa.z = a.z * scale; oa.w = a.w * scale;
    ob.x = b.x * scale; ob.y = b.y * scale; ob.z = b.z * scale; ob.w = b.w * scale;

    float4* o4 = (float4*)(ch + (size_t)row * D);
    o4[2 * lane]     = oa;
    o4[2 * lane + 1] = ob;

    union { ushort u[8]; uint4 v; } pk;
    pk.u[0] = f32_to_bf16(oa.x); pk.u[1] = f32_to_bf16(oa.y);
    pk.u[2] = f32_to_bf16(oa.z); pk.u[3] = f32_to_bf16(oa.w);
    pk.u[4] = f32_to_bf16(ob.x); pk.u[5] = f32_to_bf16(ob.y);
    pk.u[6] = f32_to_bf16(ob.z); pk.u[7] = f32_to_bf16(ob.w);
    *(uint4*)(cpk + pack_off(row, lane)) = pk.v;

    if (lane == 0) {
        const float sq = scale * scale * ss;
        y2raw[row] = sq;
        dyv[row]   = 1.0f - c * fminf(sq, MAX_NORM * MAX_NORM);
    }
}

// ---------------------------------------------------------------------------
// Kernel 3: bf16 MFMA GEMM + Poincare epilogue.  R21 VERBATIM (best known:
// 82.5 us total). 128x128 tile, BKT=32, NT=16, 4 waves (2m x 2n), 3 blk/CU.
// A: LDS dbuf 2x8KB (packed 1KB-contiguous glds16); B: per-wave registers
// (4 units, 2 async sets, depth-1). Per tile: ONE vmcnt(0)+barrier seam,
// 4 A ds_reads, 2 phases x {counted lgkmcnt; 8 MFMA}.
// Epilogue: per-wave LDS transpose + float4-coalesced stores.
// ---------------------------------------------------------------------------
#define EPST 68
#define KDIM 512
#define NT 16
#define NCOLS 4096

__global__ __launch_bounds__(256, 3)
void gemm_epi_kernel(const ushort* __restrict__ Apk,   // packed M x K bf16
                     const ushort* __restrict__ Bpk,   // packed N x K bf16
                     const float* __restrict__ x2raw,
                     const float* __restrict__ dxv,
                     const float* __restrict__ y2raw,
                     const float* __restrict__ dyv,
                     const float* __restrict__ logc,
                     float* __restrict__ out) {        // M x N
    // 18 KB: K-loop A dbuf (2 x 4096 us); epilogue reuses [0,17408).
    __shared__ __align__(16) char smem[18432];
    ushort* Asm = (ushort*)smem;

    const int tid  = threadIdx.x;
    const int lane = tid & 63;
    const int wid  = tid >> 6;     // 0..3
    const int im   = wid >> 1;     // 0..1  (64-row half)
    const int in   = wid & 1;      // 0..1  (64-col half)

    const int bn = blockIdx.x;     // 0..31
    const int bm = blockIdx.y;     // 0..63

    f32x4 acc[4][4];
#pragma unroll
    for (int m = 0; m < 4; m++)
#pragma unroll
        for (int n = 0; n < 4; n++) acc[m][n] = (f32x4){0.f, 0.f, 0.f, 0.f};

    // A staging (packed): wave w stages rowblocks bm*8 + 2w, +1 (1KB each).
    const ushort* gA0 = Apk + ((size_t)(bm * 8 + 2 * wid)) * 8192 + lane * 8;
    const ushort* gA1 = gA0 + 8192;
    ushort* lA = Asm + wid * 1024;            // + buf*4096

    // B loads (packed): wave's 4 rowblocks bn*8 + in*4 + n.
    const ushort* gB = Bpk + ((size_t)(bn * 8 + in * 4)) * 8192 + lane * 8;

    // A compute-read base: units im*4 + m at im*2048 + m*512 (+ buf*4096).
    const ushort* rdA = Asm + im * 2048 + lane * 8;

    short8 bX[4], bY[4];   // B double-buffer (parity via 2x unroll)

    // Prologue: stage A(0) into buf 0, load B(0) -> bX.
    glds16(gA0, lA);
    glds16(gA1, lA + 512);
#pragma unroll
    for (int n = 0; n < 4; n++) bX[n] = gload16(gB + n * 8192);

#define TILE_BODY(T, PAR, BCUR, BNXT)                                         \
    do {                                                                      \
        asm volatile("s_waitcnt vmcnt(0)" ::: "memory");                      \
        __builtin_amdgcn_sched_barrier(0);                                    \
        __builtin_amdgcn_s_barrier();                                         \
        if ((T) + 1 < NT) {                                                   \
            const int ko = ((T) + 1) * 512;                                   \
            BNXT[0] = gload16(gB + 0 * 8192 + ko);                            \
            BNXT[1] = gload16(gB + 1 * 8192 + ko);                            \
            BNXT[2] = gload16(gB + 2 * 8192 + ko);                            \
            BNXT[3] = gload16(gB + 3 * 8192 + ko);                            \
            glds16(gA0 + ko, lA + (((T) + 1) & 1) * 4096);                    \
            glds16(gA1 + ko, lA + (((T) + 1) & 1) * 4096 + 512);              \
        }                                                                     \
        const ushort* rA = rdA + (PAR) * 4096;                                \
        short8 a0 = ds_read128(rA);                                           \
        short8 a1 = ds_read128(rA + 512);                                     \
        short8 a2 = ds_read128(rA + 1024);                                    \
        short8 a3 = ds_read128(rA + 1536);                                    \
        asm volatile("s_waitcnt lgkmcnt(2)" ::: "memory");                    \
        __builtin_amdgcn_sched_barrier(0);                                    \
        __builtin_amdgcn_s_setprio(1);                                        \
        _Pragma("unroll")                                                     \
        for (int n = 0; n < 4; n++) {                                         \
            acc[0][n] = __builtin_amdgcn_mfma_f32_16x16x32_bf16(              \
                a0, BCUR[n], acc[0][n], 0, 0, 0);                             \
            acc[1][n] = __builtin_amdgcn_mfma_f32_16x16x32_bf16(              \
                a1, BCUR[n], acc[1][n], 0, 0, 0);                             \
        }                                                                     \
        __builtin_amdgcn_sched_barrier(0);                                    \
        __builtin_amdgcn_s_setprio(0);                                        \
        asm volatile("s_waitcnt lgkmcnt(0)" ::: "memory");                    \
        __builtin_amdgcn_sched_barrier(0);                                    \
        __builtin_amdgcn_s_setprio(1);                                        \
        _Pragma("unroll")                                                     \
        for (int n = 0; n < 4; n++) {                                         \
            acc[2][n] = __builtin_amdgcn_mfma_f32_16x16x32_bf16(              \
                a2, BCUR[n], acc[2][n], 0, 0, 0);                             \
            acc[3][n] = __builtin_amdgcn_mfma_f32_16x16x32_bf16(              \
                a3, BCUR[n], acc[3][n], 0, 0, 0);                             \
        }                                                                     \
        __builtin_amdgcn_sched_barrier(0);                                    \
        __builtin_amdgcn_s_setprio(0);                                        \
    } while (0)

#pragma unroll 1
    for (int i = 0; i < NT / 2; ++i) {
        const int te = 2 * i;
        TILE_BODY(te,     0, bX, bY);
        TILE_BODY(te + 1, 1, bY, bX);
    }
#undef TILE_BODY

    __syncthreads();   // staging LDS -> epilogue reuse safety

    // ---------------- Epilogue: LDS transpose + coalesced stores ------------
    const float c   = expf(logc[0]);
    const float rsc = 1.0f / sqrtf(c);
    const int l16 = lane & 15;
    const int lg  = lane >> 4;

    float* ep = (float*)(smem + (size_t)wid * 4352);   // [16][EPST]
    const int gr_base = bm * 128 + im * 64;
    const int gc_base = bn * 128 + in * 64;

#pragma unroll
    for (int m = 0; m < 4; m++) {
        // scatter this m-frag (16 rows x 64 cols) into the private region
#pragma unroll
        for (int n = 0; n < 4; n++)
#pragma unroll
            for (int r = 0; r < 4; r++)
                ep[(lg * 4 + r) * EPST + n * 16 + l16] = acc[m][n][r];
        asm volatile("s_waitcnt lgkmcnt(0)" ::: "memory");

        // read back row-major: 4 iters x (4 rows x 16 float4 chunks)
#pragma unroll
        for (int it = 0; it < 4; it++) {
            const int row = it * 4 + lg;                  // 0..15
            const int gr  = gr_base + m * 16 + row;
            const int gc  = gc_base + l16 * 4;
            float4 xy4 = *(const float4*)&ep[row * EPST + l16 * 4];
            const float rx  = x2raw[gr];
            const float dxr = dxv[gr];
            const float4 ry4 = *(const float4*)&y2raw[gc];
            const float4 dy4 = *(const float4*)&dyv[gc];
            float4 o;
            {
                const float rden = __builtin_amdgcn_rcpf(fmaxf(dxr * dy4.x, EPSV));
                float t = fmaxf(2.0f * c * (rx + ry4.x - 2.0f * xy4.x) * rden, EPSV);
                o.x = __logf(1.0f + t + __builtin_amdgcn_sqrtf(t * (t + 2.0f))) * rsc;
            }
            {
                const float rden = __builtin_amdgcn_rcpf(fmaxf(dxr * dy4.y, EPSV));
                float t = fmaxf(2.0f * c * (rx + ry4.y - 2.0f * xy4.y) * rden, EPSV);
                o.y = __logf(1.0f + t + __builtin_amdgcn_sqrtf(t * (t + 2.0f))) * rsc;
            }
            {
                const float rden = __builtin_amdgcn_rcpf(fmaxf(dxr * dy4.z, EPSV));
                float t = fmaxf(2.0f * c * (rx + ry4.z - 2.0f * xy4.z) * rden, EPSV);
                o.z = __logf(1.0f + t + __builtin_amdgcn_sqrtf(t * (t + 2.0f))) * rsc;
            }
            {
                const float rden = __builtin_amdgcn_rcpf(fmaxf(dxr * dy4.w, EPSV));
                float t = fmaxf(2.0f * c * (rx + ry4.w - 2.0f * xy4.w) * rden, EPSV);
                o.w = __logf(1.0f + t + __builtin_amdgcn_sqrtf(t * (t + 2.0f))) * rsc;
            }
            *(float4*)&out[(size_t)gr * NCOLS + gc] = o;
        }
        asm volatile("s_waitcnt lgkmcnt(0)" ::: "memory");
    }
}

// ---------------------------------------------------------------------------
extern "C" void kernel_launch(void* const* d_in, const int* in_sizes, int n_in,
                              void* d_out, int out_size, void* d_ws, size_t ws_size,
                              hipStream_t stream) {
    const float* emb  = (const float*)d_in[0];   // (B, D) f32
    const float* logc = (const float*)d_in[1];   // scalar f32
    const float* cen  = (const float*)d_in[2];   // (C, D) f32

    const int D = 512;
    const int B = in_sizes[0] / D;   // 8192
    const int C = in_sizes[2] / D;   // 4096

    float* out   = (float*)d_out;
    float* dists = out;                          // B*C
    float* xh    = out + (size_t)B * C;          // B*D
    float* ch    = xh + (size_t)B * D;           // C*D

    char* ws = (char*)d_ws;
    size_t off = 0;
    auto alloc = [&](size_t bytes) -> char* {
        char* p = ws + off;
        off += (bytes + 255) & ~(size_t)255;
        return p;
    };
    ushort* xpk   = (ushort*)alloc((size_t)B * D * sizeof(ushort));
    ushort* cpk   = (ushort*)alloc((size_t)C * D * sizeof(ushort));
    float*  x2raw = (float*)alloc((size_t)B * sizeof(float));
    float*  dxv   = (float*)alloc((size_t)B * sizeof(float));
    float*  y2raw = (float*)alloc((size_t)C * sizeof(float));
    float*  dyv   = (float*)alloc((size_t)C * sizeof(float));

    rows_emb_kernel<<<B / 4, 256, 0, stream>>>(emb, logc, xh, xpk, x2raw, dxv);
    rows_cen_kernel<<<C / 4, 256, 0, stream>>>(cen, logc, ch, cpk, y2raw, dyv);

    dim3 grid(C / 128, B / 128);   // (32, 64) = 2048 blocks
    gemm_epi_kernel<<<grid, 256, 0, stream>>>(xpk, cpk, x2raw, dxv, y2raw, dyv,
                                              logc, dists);
}